// Round 7
// baseline (224.582 us; speedup 1.0000x reference)
//
#include <hip/hip_runtime.h>
#include <cmath>

namespace {
constexpr int kN = 262144;           // samples (2^18)
constexpr int kL = 16;               // levels
constexpr int kT = 1 << 19;          // hash entries per level (power of 2)
constexpr unsigned kTMask = kT - 1;

typedef __attribute__((ext_vector_type(8))) short short8;      // 8 bf16 (A/B frag)
typedef __attribute__((ext_vector_type(4))) float f32x4;       // C/D frag
typedef __attribute__((ext_vector_type(4))) unsigned short ushort4v;

struct Scales { float s[kL]; };

__device__ __forceinline__ unsigned short f2bf(float f) {
    unsigned u = __builtin_bit_cast(unsigned, f);
    return (unsigned short)((u + 0x7FFFu + ((u >> 16) & 1u)) >> 16);  // RNE
}

// ---------------------------------------------------------------------------
// Kernel 0: pre-swizzle MLP weights into per-lane MFMA B-fragment order, bf16.
// Frag f, lane l, elem e at ushort index f*512 + l*8 + e.
// Frags: 0-3 w1[nt], 4-5 w2[q], 6-9 w3[nt], 10-17 w4[q*4+nt], 18-19 w5[q].
// ---------------------------------------------------------------------------
__global__ __launch_bounds__(256) void prep_w(
    const float* __restrict__ w1, const float* __restrict__ w2,
    const float* __restrict__ w3, const float* __restrict__ w4,
    const float* __restrict__ w5, unsigned short* __restrict__ out)
{
    const int i = blockIdx.x * 256 + threadIdx.x;   // 0..10239
    const int f = i >> 9;
    const int l = (i >> 3) & 63;
    const int e = i & 7;
    const int cl = l & 15;
    const int kg = l >> 4;
    float v = 0.0f;
    if (f < 4) {                 // w1: [32][64]
        v = w1[(kg * 8 + e) * 64 + f * 16 + cl];
    } else if (f < 6) {          // w2: [64][16]
        const int q = f - 4;
        v = w2[(q * 32 + kg * 8 + e) * 16 + cl];
    } else if (f < 10) {         // w3: [32][64]
        v = w3[(kg * 8 + e) * 64 + (f - 6) * 16 + cl];
    } else if (f < 18) {         // w4: [64][64]
        const int g = f - 10, q = g >> 2, nt = g & 3;
        v = w4[(q * 32 + kg * 8 + e) * 64 + nt * 16 + cl];
    } else {                     // w5: [64][3] padded to 16 cols
        const int q = f - 18;
        v = (cl < 3) ? w5[(q * 32 + kg * 8 + e) * 3 + cl] : 0.0f;
    }
    out[i] = f2bf(v);
}

// ---------------------------------------------------------------------------
// Fused kernel: hash-grid encode (x-pair trick) + MFMA MLP, one launch.
// 256 threads = 4 waves; each wave owns 64 samples and an 8 KB LDS union
// buffer (enc exchange -> h1 -> h2|SH -> c1 -> c2), wave-private: NO barriers.
// Encode: rolled 2-levels/iter loop, results written straight to LDS
// (dynamic level index is LDS-friendly; registers would spill).
// MLP: bf16 MFMA 16x16x32, fp32 accumulate, bias preloaded into C.
// ---------------------------------------------------------------------------
__global__ __launch_bounds__(256, 4) void ngp_fused(
    const float* __restrict__ pos,
    const float* __restrict__ dir,
    const float2* __restrict__ table,
    const unsigned short* __restrict__ wbf,
    const float* __restrict__ b1, const float* __restrict__ b2,
    const float* __restrict__ b3, const float* __restrict__ b4,
    const float* __restrict__ b5,
    float* __restrict__ out, Scales sc)
{
    __shared__ unsigned short ubuf[4][4096];     // 8 KB per wave (union buffer)

    const int tid = threadIdx.x;
    const int wid = tid >> 6;
    const int l   = tid & 63;
    const int cl  = l & 15;
    const int kg  = l >> 4;
    unsigned short* __restrict__ U = ubuf[wid];
    unsigned* __restrict__ U32 = reinterpret_cast<unsigned*>(U);
    const int n = blockIdx.x * 256 + tid;        // this thread's sample
    const int gbase = blockIdx.x * 256 + wid * 64;

    // ---- own-sample inputs ----
    const float px = (pos[n * 3 + 0] + 1.0f) * 0.5f;
    const float py = (pos[n * 3 + 1] + 1.0f) * 0.5f;
    const float pz = (pos[n * 3 + 2] + 1.0f) * 0.5f;
    const float dx = dir[n * 3 + 0], dy = dir[n * 3 + 1], dz = dir[n * 3 + 2];

    // ---- SH-16 into registers (stored to LDS later, after h1 is consumed) ----
    float sh[16];
    {
        const float xx = dx * dx, yy = dy * dy, zz = dz * dz;
        const float xy = dx * dy, yz = dy * dz, xz = dx * dz;
        sh[0] = 0.28209479177387814f;
        sh[1] = -0.48860251190291987f * dy;
        sh[2] = 0.48860251190291987f * dz;
        sh[3] = -0.48860251190291987f * dx;
        sh[4] = 1.0925484305920792f * xy;
        sh[5] = -1.0925484305920792f * yz;
        sh[6] = 0.94617469575755997f * zz - 0.31539156525252005f;
        sh[7] = -1.0925484305920792f * xz;
        sh[8] = 0.54627421529603959f * (xx - yy);
        sh[9] = 0.59004358992664352f * dy * (-3.0f * xx + yy);
        sh[10] = 2.8906114426405538f * xy * dz;
        sh[11] = 0.45704579946446572f * dy * (1.0f - 5.0f * zz);
        sh[12] = 0.3731763325901154f * dz * (5.0f * zz - 3.0f);
        sh[13] = 0.45704579946446572f * dx * (1.0f - 5.0f * zz);
        sh[14] = 1.445305721320277f * dz * (xx - yy);
        sh[15] = 0.59004358992664352f * dx * (xx - 3.0f * yy);
    }

    // ---- hash-grid encode: 2 levels per iteration, x-pair loads ----
    // enc exchange layout: U32[sample*18 + lvl] (pad 18 keeps b64 alignment
    // and spreads banks). 64*18*4 = 4608 B of the 8 KB buffer.
    #pragma unroll 1
    for (int lg = 0; lg < 8; ++lg) {
        float4 pr[2][4];
        float2 ex[2][4];
        unsigned idx0v[2][4], hyzv[2][4], cxv[2];
        float rx[2], ry[2], rz[2];

        #pragma unroll
        for (int t = 0; t < 2; ++t) {
            const int lv = 2 * lg + t;
            const float s = sc.s[lv];
            const float2* __restrict__ tl = table + (size_t)lv * kT;
            const float sx = px * s, sy = py * s, sz = pz * s;
            const float fx = floorf(sx), fy = floorf(sy), fz = floorf(sz);
            rx[t] = sx - fx; ry[t] = sy - fy; rz[t] = sz - fz;
            const unsigned cx = (unsigned)fx, cy = (unsigned)fy, cz = (unsigned)fz;
            cxv[t] = cx;
            const unsigned hy0 = cy * 2654435761u, hy1 = (cy + 1u) * 2654435761u;
            const unsigned hz0 = cz * 805459861u,  hz1 = (cz + 1u) * 805459861u;
            #pragma unroll
            for (int j = 0; j < 4; ++j) {              // j = oy*2 + oz
                const unsigned hyz = ((j >> 1) ? hy1 : hy0) ^ ((j & 1) ? hz1 : hz0);
                hyzv[t][j] = hyz;
                const unsigned idx0 = (cx ^ hyz) & kTMask;
                idx0v[t][j] = idx0;
                pr[t][j] = *reinterpret_cast<const float4*>(tl + (idx0 & ~1u));
            }
        }

        #pragma unroll
        for (int t = 0; t < 2; ++t) {
            if (cxv[t] & 1u) {
                const int lv = 2 * lg + t;
                const float2* __restrict__ tl = table + (size_t)lv * kT;
                const unsigned cx1 = cxv[t] + 1u;
                #pragma unroll
                for (int j = 0; j < 4; ++j)
                    ex[t][j] = tl[(cx1 ^ hyzv[t][j]) & kTMask];
            }
        }

        #pragma unroll
        for (int t = 0; t < 2; ++t) {
            const bool odd = (cxv[t] & 1u) != 0u;
            const float wx0 = 1.0f - rx[t], wx1 = rx[t];
            float f0 = 0.f, f1 = 0.f;
            #pragma unroll
            for (int j = 0; j < 4; ++j) {
                const float wyz = ((j >> 1) ? ry[t] : 1.0f - ry[t]) *
                                  ((j & 1) ? rz[t] : 1.0f - rz[t]);
                const bool hi = (idx0v[t][j] & 1u) != 0u;
                const float c0x = hi ? pr[t][j].z : pr[t][j].x;
                const float c0y = hi ? pr[t][j].w : pr[t][j].y;
                const float c1x = odd ? ex[t][j].x : (hi ? pr[t][j].x : pr[t][j].z);
                const float c1y = odd ? ex[t][j].y : (hi ? pr[t][j].y : pr[t][j].w);
                f0 = fmaf(c0x, wx0 * wyz, f0);
                f1 = fmaf(c0y, wx0 * wyz, f1);
                f0 = fmaf(c1x, wx1 * wyz, f0);
                f1 = fmaf(c1y, wx1 * wyz, f1);
            }
            U32[l * 18 + 2 * lg + t] = (unsigned)f2bf(f0) | ((unsigned)f2bf(f1) << 16);
        }
    }

    // ---- Layer 1: enc(32) -> h1(64), relu ----
    // A-frag: lane l holds sample m*16+cl, k = kg*8 + e  (k pairs = levels)
    short8 A1[4];
    #pragma unroll
    for (int m = 0; m < 4; ++m) {
        const int base = (m * 16 + cl) * 18 + kg * 4;
        const uint2 v01 = *reinterpret_cast<const uint2*>(&U32[base]);
        const uint2 v23 = *reinterpret_cast<const uint2*>(&U32[base + 2]);
        A1[m][0] = (short)(v01.x & 0xFFFFu); A1[m][1] = (short)(v01.x >> 16);
        A1[m][2] = (short)(v01.y & 0xFFFFu); A1[m][3] = (short)(v01.y >> 16);
        A1[m][4] = (short)(v23.x & 0xFFFFu); A1[m][5] = (short)(v23.x >> 16);
        A1[m][6] = (short)(v23.y & 0xFFFFu); A1[m][7] = (short)(v23.y >> 16);
    }
    {
        short8 B1[4];
        #pragma unroll
        for (int nt = 0; nt < 4; ++nt)
            B1[nt] = *reinterpret_cast<const short8*>(&wbf[(size_t)(nt) * 512 + l * 8]);

        f32x4 acc[4][4];
        #pragma unroll
        for (int nt = 0; nt < 4; ++nt) {
            const float bv = b1[nt * 16 + cl];
            #pragma unroll
            for (int m = 0; m < 4; ++m) {
                acc[m][nt][0] = bv; acc[m][nt][1] = bv; acc[m][nt][2] = bv; acc[m][nt][3] = bv;
            }
        }
        #pragma unroll
        for (int m = 0; m < 4; ++m)
            #pragma unroll
            for (int nt = 0; nt < 4; ++nt)
                acc[m][nt] = __builtin_amdgcn_mfma_f32_16x16x32_bf16(A1[m], B1[nt], acc[m][nt], 0, 0, 0);

        // h1 -> U, layout: (s>>4)*1024 + k*16 + (s&15), k<64 (8 KB)
        #pragma unroll
        for (int m = 0; m < 4; ++m) {
            #pragma unroll
            for (int nt = 0; nt < 4; ++nt) {
                ushort4v pk;
                #pragma unroll
                for (int r = 0; r < 4; ++r) pk[r] = f2bf(fmaxf(acc[m][nt][r], 0.0f));
                *reinterpret_cast<ushort4v*>(&U[m * 1024 + (nt * 16 + cl) * 16 + kg * 4]) = pk;
            }
        }
    }

    // ---- Layer 2: h1(64) -> h2(16); density = exp(h2[0]) ----
    {
        short8 A2[4][2];
        #pragma unroll
        for (int m = 0; m < 4; ++m)
            #pragma unroll
            for (int q = 0; q < 2; ++q)
                #pragma unroll
                for (int e = 0; e < 8; ++e)
                    A2[m][q][e] = (short)U[m * 1024 + (q * 32 + kg * 8 + e) * 16 + cl];

        short8 B2[2];
        #pragma unroll
        for (int q = 0; q < 2; ++q)
            B2[q] = *reinterpret_cast<const short8*>(&wbf[(size_t)(4 + q) * 512 + l * 8]);

        f32x4 acc[4];
        const float bv = b2[cl];
        #pragma unroll
        for (int m = 0; m < 4; ++m) { acc[m][0] = bv; acc[m][1] = bv; acc[m][2] = bv; acc[m][3] = bv; }
        #pragma unroll
        for (int m = 0; m < 4; ++m)
            #pragma unroll
            for (int q = 0; q < 2; ++q)
                acc[m] = __builtin_amdgcn_mfma_f32_16x16x32_bf16(A2[m][q], B2[q], acc[m], 0, 0, 0);

        // h2 + SH -> U, layout: (s>>4)*512 + k*16 + (s&15), k<32 (4 KB)
        #pragma unroll
        for (int m = 0; m < 4; ++m) {
            if (cl == 0) {
                #pragma unroll
                for (int r = 0; r < 4; ++r)
                    out[(size_t)(gbase + m * 16 + kg * 4 + r) * 4 + 0] = expf(acc[m][r]);
            }
            ushort4v pk;
            #pragma unroll
            for (int r = 0; r < 4; ++r) pk[r] = f2bf(acc[m][r]);
            *reinterpret_cast<ushort4v*>(&U[m * 512 + cl * 16 + kg * 4]) = pk;
        }
        #pragma unroll
        for (int j = 0; j < 16; ++j)
            U[(l >> 4) * 512 + (16 + j) * 16 + (l & 15)] = f2bf(sh[j]);
    }

    // ---- Layer 3: [h2|SH](32) -> c1(64), relu ----
    {
        short8 A3[4];
        #pragma unroll
        for (int m = 0; m < 4; ++m)
            #pragma unroll
            for (int e = 0; e < 8; ++e)
                A3[m][e] = (short)U[m * 512 + (kg * 8 + e) * 16 + cl];

        short8 B3[4];
        #pragma unroll
        for (int nt = 0; nt < 4; ++nt)
            B3[nt] = *reinterpret_cast<const short8*>(&wbf[(size_t)(6 + nt) * 512 + l * 8]);

        f32x4 acc[4][4];
        #pragma unroll
        for (int nt = 0; nt < 4; ++nt) {
            const float bv = b3[nt * 16 + cl];
            #pragma unroll
            for (int m = 0; m < 4; ++m) {
                acc[m][nt][0] = bv; acc[m][nt][1] = bv; acc[m][nt][2] = bv; acc[m][nt][3] = bv;
            }
        }
        #pragma unroll
        for (int m = 0; m < 4; ++m)
            #pragma unroll
            for (int nt = 0; nt < 4; ++nt)
                acc[m][nt] = __builtin_amdgcn_mfma_f32_16x16x32_bf16(A3[m], B3[nt], acc[m][nt], 0, 0, 0);

        #pragma unroll
        for (int m = 0; m < 4; ++m) {
            #pragma unroll
            for (int nt = 0; nt < 4; ++nt) {
                ushort4v pk;
                #pragma unroll
                for (int r = 0; r < 4; ++r) pk[r] = f2bf(fmaxf(acc[m][nt][r], 0.0f));
                *reinterpret_cast<ushort4v*>(&U[m * 1024 + (nt * 16 + cl) * 16 + kg * 4]) = pk;
            }
        }
    }

    // ---- Layer 4: c1(64) -> c2(64), relu ----
    {
        short8 A4[4][2];
        #pragma unroll
        for (int m = 0; m < 4; ++m)
            #pragma unroll
            for (int q = 0; q < 2; ++q)
                #pragma unroll
                for (int e = 0; e < 8; ++e)
                    A4[m][q][e] = (short)U[m * 1024 + (q * 32 + kg * 8 + e) * 16 + cl];

        short8 B4[2][4];
        #pragma unroll
        for (int q = 0; q < 2; ++q)
            #pragma unroll
            for (int nt = 0; nt < 4; ++nt)
                B4[q][nt] = *reinterpret_cast<const short8*>(&wbf[(size_t)(10 + q * 4 + nt) * 512 + l * 8]);

        f32x4 acc[4][4];
        #pragma unroll
        for (int nt = 0; nt < 4; ++nt) {
            const float bv = b4[nt * 16 + cl];
            #pragma unroll
            for (int m = 0; m < 4; ++m) {
                acc[m][nt][0] = bv; acc[m][nt][1] = bv; acc[m][nt][2] = bv; acc[m][nt][3] = bv;
            }
        }
        #pragma unroll
        for (int m = 0; m < 4; ++m)
            #pragma unroll
            for (int nt = 0; nt < 4; ++nt)
                #pragma unroll
                for (int q = 0; q < 2; ++q)
                    acc[m][nt] = __builtin_amdgcn_mfma_f32_16x16x32_bf16(A4[m][q], B4[q][nt], acc[m][nt], 0, 0, 0);

        #pragma unroll
        for (int m = 0; m < 4; ++m) {
            #pragma unroll
            for (int nt = 0; nt < 4; ++nt) {
                ushort4v pk;
                #pragma unroll
                for (int r = 0; r < 4; ++r) pk[r] = f2bf(fmaxf(acc[m][nt][r], 0.0f));
                *reinterpret_cast<ushort4v*>(&U[m * 1024 + (nt * 16 + cl) * 16 + kg * 4]) = pk;
            }
        }
    }

    // ---- Layer 5: c2(64) -> 3, sigmoid ----
    {
        short8 A5[4][2];
        #pragma unroll
        for (int m = 0; m < 4; ++m)
            #pragma unroll
            for (int q = 0; q < 2; ++q)
                #pragma unroll
                for (int e = 0; e < 8; ++e)
                    A5[m][q][e] = (short)U[m * 1024 + (q * 32 + kg * 8 + e) * 16 + cl];

        short8 B5[2];
        #pragma unroll
        for (int q = 0; q < 2; ++q)
            B5[q] = *reinterpret_cast<const short8*>(&wbf[(size_t)(18 + q) * 512 + l * 8]);

        f32x4 acc[4];
        const float bv = (cl < 3) ? b5[cl] : 0.0f;
        #pragma unroll
        for (int m = 0; m < 4; ++m) { acc[m][0] = bv; acc[m][1] = bv; acc[m][2] = bv; acc[m][3] = bv; }
        #pragma unroll
        for (int m = 0; m < 4; ++m)
            #pragma unroll
            for (int q = 0; q < 2; ++q)
                acc[m] = __builtin_amdgcn_mfma_f32_16x16x32_bf16(A5[m][q], B5[q], acc[m], 0, 0, 0);

        if (cl < 3) {
            #pragma unroll
            for (int m = 0; m < 4; ++m)
                #pragma unroll
                for (int r = 0; r < 4; ++r)
                    out[(size_t)(gbase + m * 16 + kg * 4 + r) * 4 + 1 + cl] =
                        1.0f / (1.0f + expf(-acc[m][r]));
        }
    }
}

} // namespace

extern "C" void kernel_launch(void* const* d_in, const int* in_sizes, int n_in,
                              void* d_out, int out_size, void* d_ws, size_t ws_size,
                              hipStream_t stream) {
    (void)in_sizes; (void)n_in; (void)out_size; (void)ws_size;

    Scales sc;
    const double g = exp((log(2048.0) - log(16.0)) / 15.0);
    for (int l = 0; l < kL; ++l) sc.s[l] = (float)floor(16.0 * pow(g, (double)l));

    const float*  pos   = (const float*)d_in[0];
    const float*  dir   = (const float*)d_in[1];
    const float2* table = (const float2*)d_in[2];
    const float *w1 = (const float*)d_in[3],  *b1 = (const float*)d_in[4];
    const float *w2 = (const float*)d_in[5],  *b2 = (const float*)d_in[6];
    const float *w3 = (const float*)d_in[7],  *b3 = (const float*)d_in[8];
    const float *w4 = (const float*)d_in[9],  *b4 = (const float*)d_in[10];
    const float *w5 = (const float*)d_in[11], *b5 = (const float*)d_in[12];
    float* out = (float*)d_out;

    unsigned short* wbf = (unsigned short*)d_ws;   // 20480 ushorts = 40 KB

    prep_w<<<40, 256, 0, stream>>>(w1, w2, w3, w4, w5, wbf);
    ngp_fused<<<kN / 256, 256, 0, stream>>>(pos, dir, table, wbf,
        b1, b2, b3, b4, b5, out, sc);
}

// Round 8
// 147.409 us; speedup vs baseline: 1.5235x; 1.5235x over previous
//
#include <hip/hip_runtime.h>
#include <cmath>

namespace {
constexpr int kN = 262144;           // samples (2^18)
constexpr int kL = 16;               // levels
constexpr int kT = 1 << 19;          // hash entries per level (power of 2)
constexpr unsigned kTMask = kT - 1;

typedef __attribute__((ext_vector_type(8))) short short8;      // 8 bf16 (A/B frag)
typedef __attribute__((ext_vector_type(4))) float f32x4;       // C/D frag
typedef __attribute__((ext_vector_type(4))) unsigned short ushort4v;

struct Scales { float s[kL]; };

__device__ __forceinline__ unsigned short f2bf(float f) {
    unsigned u = __builtin_bit_cast(unsigned, f);
    return (unsigned short)((u + 0x7FFFu + ((u >> 16) & 1u)) >> 16);  // RNE
}

// ---------------------------------------------------------------------------
// Kernel 0: pre-swizzle MLP weights into per-lane MFMA B-fragment order, bf16.
// ---------------------------------------------------------------------------
__global__ __launch_bounds__(256) void prep_w(
    const float* __restrict__ w1, const float* __restrict__ w2,
    const float* __restrict__ w3, const float* __restrict__ w4,
    const float* __restrict__ w5, unsigned short* __restrict__ out)
{
    const int i = blockIdx.x * 256 + threadIdx.x;   // 0..10239
    const int f = i >> 9;
    const int l = (i >> 3) & 63;
    const int e = i & 7;
    const int cl = l & 15;
    const int kg = l >> 4;
    float v = 0.0f;
    if (f < 4) {                 // w1: [32][64]
        v = w1[(kg * 8 + e) * 64 + f * 16 + cl];
    } else if (f < 6) {          // w2: [64][16]
        const int q = f - 4;
        v = w2[(q * 32 + kg * 8 + e) * 16 + cl];
    } else if (f < 10) {         // w3: [32][64]
        v = w3[(kg * 8 + e) * 64 + (f - 6) * 16 + cl];
    } else if (f < 18) {         // w4: [64][64]
        const int g = f - 10, q = g >> 2, nt = g & 3;
        v = w4[(q * 32 + kg * 8 + e) * 64 + nt * 16 + cl];
    } else {                     // w5: [64][3] padded to 16 cols
        const int q = f - 18;
        v = (cl < 3) ? w5[(q * 32 + kg * 8 + e) * 3 + cl] : 0.0f;
    }
    out[i] = f2bf(v);
}

// ---------------------------------------------------------------------------
// Kernel 1: hash-grid encode, 1 sample/thread, x-corner PAIR loads.
// Request-count floor: 4 pair loads (+4 predicated extras for odd cx) = 6 avg
// lane-requests per (sample,level). 1 sample/thread maximizes occupancy and
// issue rate (R3: 0.39 req/cy/CU at 80% occ vs R6: 0.32 at 59%).
// Level is block-uniform (bid>>10) -> temporal L2 locality per level slice.
// ---------------------------------------------------------------------------
__global__ __launch_bounds__(256) void ngp_encode(
    const float* __restrict__ pos,
    const float2* __restrict__ table,
    unsigned* __restrict__ enc,
    Scales sc)
{
    const int bid = blockIdx.x;
    const int l = bid >> 10;                           // block-uniform level
    const int n = ((bid & 1023) << 8) | threadIdx.x;   // sample

    const float s = sc.s[l];
    const float2* __restrict__ tl = table + (size_t)l * kT;

    const float px = (pos[n * 3 + 0] + 1.0f) * 0.5f;
    const float py = (pos[n * 3 + 1] + 1.0f) * 0.5f;
    const float pz = (pos[n * 3 + 2] + 1.0f) * 0.5f;
    const float sx = px * s, sy = py * s, sz = pz * s;
    const float fx = floorf(sx), fy = floorf(sy), fz = floorf(sz);
    const float rx = sx - fx, ry = sy - fy, rz = sz - fz;
    const unsigned cx = (unsigned)fx, cy = (unsigned)fy, cz = (unsigned)fz;

    const unsigned hy0 = cy * 2654435761u, hy1 = (cy + 1u) * 2654435761u;
    const unsigned hz0 = cz * 805459861u,  hz1 = (cz + 1u) * 805459861u;

    float4 pr[4];          // pair loads (both x-corners when cx even)
    float2 ex[4];          // extra loads for odd cx
    unsigned idx0v[4], hyzv[4];

    // phase 1: address math + issue all 4 pair loads back-to-back
    #pragma unroll
    for (int j = 0; j < 4; ++j) {              // j = oy*2 + oz
        const unsigned hyz = ((j >> 1) ? hy1 : hy0) ^ ((j & 1) ? hz1 : hz0);
        hyzv[j] = hyz;
        const unsigned idx0 = (cx ^ hyz) & kTMask;
        idx0v[j] = idx0;
        pr[j] = *reinterpret_cast<const float4*>(tl + (idx0 & ~1u));
    }

    // phase 2: predicated extras (only odd-cx lanes issue requests)
    if (cx & 1u) {
        const unsigned cx1 = cx + 1u;
        #pragma unroll
        for (int j = 0; j < 4; ++j)
            ex[j] = tl[(cx1 ^ hyzv[j]) & kTMask];
    }

    // phase 3: trilinear combine
    const bool odd = (cx & 1u) != 0u;
    const float wx0 = 1.0f - rx, wx1 = rx;
    float f0 = 0.f, f1 = 0.f;
    #pragma unroll
    for (int j = 0; j < 4; ++j) {
        const float wyz = ((j >> 1) ? ry : 1.0f - ry) *
                          ((j & 1) ? rz : 1.0f - rz);
        const bool hi = (idx0v[j] & 1u) != 0u;
        const float c0x = hi ? pr[j].z : pr[j].x;
        const float c0y = hi ? pr[j].w : pr[j].y;
        const float c1x = odd ? ex[j].x : (hi ? pr[j].x : pr[j].z);
        const float c1y = odd ? ex[j].y : (hi ? pr[j].y : pr[j].w);
        f0 = fmaf(c0x, wx0 * wyz, f0);
        f1 = fmaf(c0y, wx0 * wyz, f1);
        f0 = fmaf(c1x, wx1 * wyz, f0);
        f1 = fmaf(c1y, wx1 * wyz, f1);
    }
    enc[(size_t)l * kN + n] = (unsigned)f2bf(f0) | ((unsigned)f2bf(f1) << 16);
}

// ---------------------------------------------------------------------------
// Kernel 2: fully-fused MLP via MFMA. 4 waves/block, 64 samples/wave,
// wave-private LDS (no __syncthreads). bf16 in, fp32 accumulate.
// ---------------------------------------------------------------------------
__global__ __launch_bounds__(256) void ngp_mlp_mfma(
    const unsigned* __restrict__ enc,
    const unsigned short* __restrict__ wbf,
    const float* __restrict__ dir,
    const float* __restrict__ b1, const float* __restrict__ b2,
    const float* __restrict__ b3, const float* __restrict__ b4,
    const float* __restrict__ b5,
    float* __restrict__ out)
{
    __shared__ unsigned short sA[4][4096];   // 64k x 64s per wave
    __shared__ unsigned short sB[4][2048];   // 32k x 64s per wave

    const int tid = threadIdx.x;
    const int wid = tid >> 6;
    const int l   = tid & 63;
    const int cl  = l & 15;
    const int kg  = l >> 4;
    unsigned short* __restrict__ A_ = sA[wid];
    unsigned short* __restrict__ B_ = sB[wid];
    const int gbase = blockIdx.x * 256 + wid * 64;

    // ---- SH-16 for this lane's own sample, written to bufB k=16..31 ----
    {
        const int s = gbase + l;
        const float x = dir[s * 3 + 0], y = dir[s * 3 + 1], z = dir[s * 3 + 2];
        const float xx = x * x, yy = y * y, zz = z * z;
        const float xy = x * y, yz = y * z, xz = x * z;
        float sh[16];
        sh[0] = 0.28209479177387814f;
        sh[1] = -0.48860251190291987f * y;
        sh[2] = 0.48860251190291987f * z;
        sh[3] = -0.48860251190291987f * x;
        sh[4] = 1.0925484305920792f * xy;
        sh[5] = -1.0925484305920792f * yz;
        sh[6] = 0.94617469575755997f * zz - 0.31539156525252005f;
        sh[7] = -1.0925484305920792f * xz;
        sh[8] = 0.54627421529603959f * (xx - yy);
        sh[9] = 0.59004358992664352f * y * (-3.0f * xx + yy);
        sh[10] = 2.8906114426405538f * xy * z;
        sh[11] = 0.45704579946446572f * y * (1.0f - 5.0f * zz);
        sh[12] = 0.3731763325901154f * z * (5.0f * zz - 3.0f);
        sh[13] = 0.45704579946446572f * x * (1.0f - 5.0f * zz);
        sh[14] = 1.445305721320277f * z * (xx - yy);
        sh[15] = 0.59004358992664352f * x * (xx - 3.0f * yy);
        #pragma unroll
        for (int j = 0; j < 16; ++j)
            B_[(l >> 4) * 512 + (16 + j) * 16 + (l & 15)] = f2bf(sh[j]);
    }

    // ---- Layer 1: enc(32) -> h1(64), relu ----
    short8 A1[4];
    #pragma unroll
    for (int m = 0; m < 4; ++m) {
        #pragma unroll
        for (int j = 0; j < 4; ++j) {
            const unsigned v = enc[(size_t)(kg * 4 + j) * kN + (gbase + m * 16 + cl)];
            A1[m][2 * j]     = (short)(v & 0xFFFFu);
            A1[m][2 * j + 1] = (short)(v >> 16);
        }
    }
    {
        short8 B1[4];
        #pragma unroll
        for (int nt = 0; nt < 4; ++nt)
            B1[nt] = *reinterpret_cast<const short8*>(&wbf[(size_t)(nt) * 512 + l * 8]);

        f32x4 acc[4][4];
        #pragma unroll
        for (int nt = 0; nt < 4; ++nt) {
            const float bv = b1[nt * 16 + cl];
            #pragma unroll
            for (int m = 0; m < 4; ++m) {
                acc[m][nt][0] = bv; acc[m][nt][1] = bv; acc[m][nt][2] = bv; acc[m][nt][3] = bv;
            }
        }
        #pragma unroll
        for (int m = 0; m < 4; ++m)
            #pragma unroll
            for (int nt = 0; nt < 4; ++nt)
                acc[m][nt] = __builtin_amdgcn_mfma_f32_16x16x32_bf16(A1[m], B1[nt], acc[m][nt], 0, 0, 0);

        #pragma unroll
        for (int m = 0; m < 4; ++m) {
            #pragma unroll
            for (int nt = 0; nt < 4; ++nt) {
                ushort4v pk;
                #pragma unroll
                for (int r = 0; r < 4; ++r) pk[r] = f2bf(fmaxf(acc[m][nt][r], 0.0f));
                *reinterpret_cast<ushort4v*>(&A_[m * 1024 + (nt * 16 + cl) * 16 + kg * 4]) = pk;
            }
        }
    }

    // ---- Layer 2: h1(64) -> h2(16), no relu; density = exp(h2[0]) ----
    {
        short8 A2[4][2];
        #pragma unroll
        for (int m = 0; m < 4; ++m)
            #pragma unroll
            for (int q = 0; q < 2; ++q)
                #pragma unroll
                for (int e = 0; e < 8; ++e)
                    A2[m][q][e] = (short)A_[m * 1024 + (q * 32 + kg * 8 + e) * 16 + cl];

        short8 B2[2];
        #pragma unroll
        for (int q = 0; q < 2; ++q)
            B2[q] = *reinterpret_cast<const short8*>(&wbf[(size_t)(4 + q) * 512 + l * 8]);

        f32x4 acc[4];
        const float bv = b2[cl];
        #pragma unroll
        for (int m = 0; m < 4; ++m) { acc[m][0] = bv; acc[m][1] = bv; acc[m][2] = bv; acc[m][3] = bv; }
        #pragma unroll
        for (int m = 0; m < 4; ++m)
            #pragma unroll
            for (int q = 0; q < 2; ++q)
                acc[m] = __builtin_amdgcn_mfma_f32_16x16x32_bf16(A2[m][q], B2[q], acc[m], 0, 0, 0);

        #pragma unroll
        for (int m = 0; m < 4; ++m) {
            if (cl == 0) {
                #pragma unroll
                for (int r = 0; r < 4; ++r)
                    out[(size_t)(gbase + m * 16 + kg * 4 + r) * 4 + 0] = expf(acc[m][r]);
            }
            ushort4v pk;
            #pragma unroll
            for (int r = 0; r < 4; ++r) pk[r] = f2bf(acc[m][r]);
            *reinterpret_cast<ushort4v*>(&B_[m * 512 + cl * 16 + kg * 4]) = pk;
        }
    }

    // ---- Layer 3: [h2|SH](32) -> c1(64), relu ----
    {
        short8 A3[4];
        #pragma unroll
        for (int m = 0; m < 4; ++m)
            #pragma unroll
            for (int e = 0; e < 8; ++e)
                A3[m][e] = (short)B_[m * 512 + (kg * 8 + e) * 16 + cl];

        short8 B3[4];
        #pragma unroll
        for (int nt = 0; nt < 4; ++nt)
            B3[nt] = *reinterpret_cast<const short8*>(&wbf[(size_t)(6 + nt) * 512 + l * 8]);

        f32x4 acc[4][4];
        #pragma unroll
        for (int nt = 0; nt < 4; ++nt) {
            const float bv = b3[nt * 16 + cl];
            #pragma unroll
            for (int m = 0; m < 4; ++m) {
                acc[m][nt][0] = bv; acc[m][nt][1] = bv; acc[m][nt][2] = bv; acc[m][nt][3] = bv;
            }
        }
        #pragma unroll
        for (int m = 0; m < 4; ++m)
            #pragma unroll
            for (int nt = 0; nt < 4; ++nt)
                acc[m][nt] = __builtin_amdgcn_mfma_f32_16x16x32_bf16(A3[m], B3[nt], acc[m][nt], 0, 0, 0);

        #pragma unroll
        for (int m = 0; m < 4; ++m) {
            #pragma unroll
            for (int nt = 0; nt < 4; ++nt) {
                ushort4v pk;
                #pragma unroll
                for (int r = 0; r < 4; ++r) pk[r] = f2bf(fmaxf(acc[m][nt][r], 0.0f));
                *reinterpret_cast<ushort4v*>(&A_[m * 1024 + (nt * 16 + cl) * 16 + kg * 4]) = pk;
            }
        }
    }

    // ---- Layer 4: c1(64) -> c2(64), relu ----
    {
        short8 A4[4][2];
        #pragma unroll
        for (int m = 0; m < 4; ++m)
            #pragma unroll
            for (int q = 0; q < 2; ++q)
                #pragma unroll
                for (int e = 0; e < 8; ++e)
                    A4[m][q][e] = (short)A_[m * 1024 + (q * 32 + kg * 8 + e) * 16 + cl];

        short8 B4[2][4];
        #pragma unroll
        for (int q = 0; q < 2; ++q)
            #pragma unroll
            for (int nt = 0; nt < 4; ++nt)
                B4[q][nt] = *reinterpret_cast<const short8*>(&wbf[(size_t)(10 + q * 4 + nt) * 512 + l * 8]);

        f32x4 acc[4][4];
        #pragma unroll
        for (int nt = 0; nt < 4; ++nt) {
            const float bv = b4[nt * 16 + cl];
            #pragma unroll
            for (int m = 0; m < 4; ++m) {
                acc[m][nt][0] = bv; acc[m][nt][1] = bv; acc[m][nt][2] = bv; acc[m][nt][3] = bv;
            }
        }
        #pragma unroll
        for (int m = 0; m < 4; ++m)
            #pragma unroll
            for (int nt = 0; nt < 4; ++nt)
                #pragma unroll
                for (int q = 0; q < 2; ++q)
                    acc[m][nt] = __builtin_amdgcn_mfma_f32_16x16x32_bf16(A4[m][q], B4[q][nt], acc[m][nt], 0, 0, 0);

        #pragma unroll
        for (int m = 0; m < 4; ++m) {
            #pragma unroll
            for (int nt = 0; nt < 4; ++nt) {
                ushort4v pk;
                #pragma unroll
                for (int r = 0; r < 4; ++r) pk[r] = f2bf(fmaxf(acc[m][nt][r], 0.0f));
                *reinterpret_cast<ushort4v*>(&A_[m * 1024 + (nt * 16 + cl) * 16 + kg * 4]) = pk;
            }
        }
    }

    // ---- Layer 5: c2(64) -> 3, sigmoid ----
    {
        short8 A5[4][2];
        #pragma unroll
        for (int m = 0; m < 4; ++m)
            #pragma unroll
            for (int q = 0; q < 2; ++q)
                #pragma unroll
                for (int e = 0; e < 8; ++e)
                    A5[m][q][e] = (short)A_[m * 1024 + (q * 32 + kg * 8 + e) * 16 + cl];

        short8 B5[2];
        #pragma unroll
        for (int q = 0; q < 2; ++q)
            B5[q] = *reinterpret_cast<const short8*>(&wbf[(size_t)(18 + q) * 512 + l * 8]);

        f32x4 acc[4];
        const float bv = (cl < 3) ? b5[cl] : 0.0f;
        #pragma unroll
        for (int m = 0; m < 4; ++m) { acc[m][0] = bv; acc[m][1] = bv; acc[m][2] = bv; acc[m][3] = bv; }
        #pragma unroll
        for (int m = 0; m < 4; ++m)
            #pragma unroll
            for (int q = 0; q < 2; ++q)
                acc[m] = __builtin_amdgcn_mfma_f32_16x16x32_bf16(A5[m][q], B5[q], acc[m], 0, 0, 0);

        if (cl < 3) {
            #pragma unroll
            for (int m = 0; m < 4; ++m)
                #pragma unroll
                for (int r = 0; r < 4; ++r)
                    out[(size_t)(gbase + m * 16 + kg * 4 + r) * 4 + 1 + cl] =
                        1.0f / (1.0f + expf(-acc[m][r]));
        }
    }
}

} // namespace

extern "C" void kernel_launch(void* const* d_in, const int* in_sizes, int n_in,
                              void* d_out, int out_size, void* d_ws, size_t ws_size,
                              hipStream_t stream) {
    (void)in_sizes; (void)n_in; (void)out_size; (void)ws_size;

    Scales sc;
    const double g = exp((log(2048.0) - log(16.0)) / 15.0);
    for (int l = 0; l < kL; ++l) sc.s[l] = (float)floor(16.0 * pow(g, (double)l));

    const float*  pos   = (const float*)d_in[0];
    const float*  dir   = (const float*)d_in[1];
    const float2* table = (const float2*)d_in[2];
    const float *w1 = (const float*)d_in[3],  *b1 = (const float*)d_in[4];
    const float *w2 = (const float*)d_in[5],  *b2 = (const float*)d_in[6];
    const float *w3 = (const float*)d_in[7],  *b3 = (const float*)d_in[8];
    const float *w4 = (const float*)d_in[9],  *b4 = (const float*)d_in[10];
    const float *w5 = (const float*)d_in[11], *b5 = (const float*)d_in[12];
    float* out = (float*)d_out;

    // ws layout: [0, 20480) bf16 weight frags; [32768, 32768 + 16*kN*4) packed enc
    unsigned short* wbf = (unsigned short*)d_ws;
    unsigned* enc = (unsigned*)((char*)d_ws + 32768);

    prep_w<<<40, 256, 0, stream>>>(w1, w2, w3, w4, w5, wbf);
    ngp_encode<<<kL * 1024, 256, 0, stream>>>(pos, table, enc, sc);
    ngp_mlp_mfma<<<kN / 256, 256, 0, stream>>>(enc, wbf, dir,
        b1, b2, b3, b4, b5, out);
}